// Round 5
// baseline (103.396 us; speedup 1.0000x reference)
//
#include <hip/hip_runtime.h>

// GBDT ensemble inference — R5: lane = batch row (64 rows/block), one tree per
// gather instruction. B=32768, T=512, D=8, F=512, C=1.
//
// TA/TCP line-throughput model: with 64 lanes all walking the SAME tree, each
// level-l gather touches only that tree's 2^(l+1)-entry window (<=1KB), so
// lines/instr = min(64, window_lines) instead of 4 trees' worth. ~0.76
// lines/walk vs 2.25 in R4 (3x less TA work). Each wave owns 32 trees,
// 4 interleaved chains (4 adjacent trees) for MLP; lane accumulates 4
// consecutive trees' leaves in registers -> direct float4 store (no os LDS).

#define BB 32768
#define TT 512
#define FF 512
#define PADW 65536        // T * 2^(D-1)
#define NLV 7             // internal levels below root
#define ROWS 64           // batch rows per block (= lanes per wave)
#define THREADS 1024      // 16 waves
#define WAVES 16
#define TPW 32            // trees per wave = 512/16
#define XSS 516           // xs row stride in floats (rows shift 4 banks each)

__global__ __launch_bounds__(256) void pack_tables_kernel(
    const int* __restrict__ nodes_lv, const float* __restrict__ biases_lv,
    int2* __restrict__ packed, int n)
{
    int i = blockIdx.x * 256 + threadIdx.x;
    if (i < n) packed[i] = make_int2(nodes_lv[i], __float_as_int(biases_lv[i]));
}

template<bool PACKED>
__global__ __launch_bounds__(THREADS) void gbdt_walk_kernel(
    const float* __restrict__ x,
    const int*   __restrict__ root_nodes,
    const float* __restrict__ root_biases,
    const int*   __restrict__ tree_indices,
    const int*   __restrict__ nodes_lv,
    const float* __restrict__ biases_lv,
    const float* __restrict__ leaf_nodes,
    const int2*  __restrict__ packed,
    float*       __restrict__ out)
{
    __shared__ float xs[ROWS * XSS];        // 132,096 B

    const int tid = threadIdx.x;
    const int b0  = blockIdx.x * ROWS;

    // ---- stage 64 x-rows into LDS (coalesced float4, 8 iters) ----
    const float4* __restrict__ xr = (const float4*)(x + (size_t)b0 * FF);
    #pragma unroll
    for (int i = 0; i < (ROWS * FF / 4) / THREADS; ++i) {   // 8 iters
        int fidx = i * THREADS + tid;       // float4 index over [ROWS][FF/4]
        int r = fidx >> 7, c4 = fidx & 127;
        float4 v = xr[fidx];
        *(float4*)&xs[r * XSS + (c4 << 2)] = v;
    }
    __syncthreads();

    // ---- walk: lane = row; wave walks its 32 trees, 4 chains/step ----
    const int wv   = tid >> 6;              // wave 0..15
    const int lane = tid & 63;              // row 0..63
    const int tb   = wv * TPW;
    const float* __restrict__ xrow = &xs[lane * XSS];
    float* __restrict__ orow = out + (size_t)(b0 + lane) * TT;

    #pragma unroll
    for (int s = 0; s < TPW / 4; ++s) {     // 8 steps, 4 interleaved chains
        // wave-uniform tree ids -> scalar loads for root tables
        const int t0 = __builtin_amdgcn_readfirstlane(tb + 4 * s);
        int p0 = tree_indices[t0+0] + (xrow[root_nodes[t0+0]] >= root_biases[t0+0] ? 1 : 0);
        int p1 = tree_indices[t0+1] + (xrow[root_nodes[t0+1]] >= root_biases[t0+1] ? 1 : 0);
        int p2 = tree_indices[t0+2] + (xrow[root_nodes[t0+2]] >= root_biases[t0+2] ? 1 : 0);
        int p3 = tree_indices[t0+3] + (xrow[root_nodes[t0+3]] >= root_biases[t0+3] ? 1 : 0);
        #pragma unroll
        for (int l = 0; l < NLV; ++l) {
            if constexpr (PACKED) {
                const int2 n0 = packed[l * PADW + p0];
                const int2 n1 = packed[l * PADW + p1];
                const int2 n2 = packed[l * PADW + p2];
                const int2 n3 = packed[l * PADW + p3];
                p0 = 2 * p0 + (xrow[n0.x] >= __int_as_float(n0.y) ? 1 : 0);
                p1 = 2 * p1 + (xrow[n1.x] >= __int_as_float(n1.y) ? 1 : 0);
                p2 = 2 * p2 + (xrow[n2.x] >= __int_as_float(n2.y) ? 1 : 0);
                p3 = 2 * p3 + (xrow[n3.x] >= __int_as_float(n3.y) ? 1 : 0);
            } else {
                const int   f0 = nodes_lv[l * PADW + p0];
                const int   f1 = nodes_lv[l * PADW + p1];
                const int   f2 = nodes_lv[l * PADW + p2];
                const int   f3 = nodes_lv[l * PADW + p3];
                const float h0 = biases_lv[l * PADW + p0];
                const float h1 = biases_lv[l * PADW + p1];
                const float h2 = biases_lv[l * PADW + p2];
                const float h3 = biases_lv[l * PADW + p3];
                p0 = 2 * p0 + (xrow[f0] >= h0 ? 1 : 0);
                p1 = 2 * p1 + (xrow[f1] >= h1 ? 1 : 0);
                p2 = 2 * p2 + (xrow[f2] >= h2 ? 1 : 0);
                p3 = 2 * p3 + (xrow[f3] >= h3 ? 1 : 0);
            }
        }
        // leaves for 4 consecutive trees live in this lane -> direct float4
        const float v0 = leaf_nodes[p0];
        const float v1 = leaf_nodes[p1];
        const float v2 = leaf_nodes[p2];
        const float v3 = leaf_nodes[p3];
        *(float4*)&orow[t0] = make_float4(v0, v1, v2, v3);
    }
}

extern "C" void kernel_launch(void* const* d_in, const int* in_sizes, int n_in,
                              void* d_out, int out_size, void* d_ws, size_t ws_size,
                              hipStream_t stream) {
    const float* x            = (const float*)d_in[0];
    const int*   root_nodes   = (const int*)  d_in[1];
    const float* root_biases  = (const float*)d_in[2];
    const int*   tree_indices = (const int*)  d_in[3];
    const int*   nodes_lv     = (const int*)  d_in[4];
    const float* biases_lv    = (const float*)d_in[5];
    const float* leaf_nodes   = (const float*)d_in[6];
    float*       out          = (float*)d_out;

    const int n_nodes = NLV * PADW;                     // 458,752
    const size_t packed_bytes = (size_t)n_nodes * 8;    // 3.67 MB

    dim3 grid(BB / ROWS);   // 512 blocks
    dim3 block(THREADS);

    if (ws_size >= packed_bytes) {
        int2* packed = (int2*)d_ws;
        pack_tables_kernel<<<(n_nodes + 255) / 256, 256, 0, stream>>>(
            nodes_lv, biases_lv, packed, n_nodes);
        gbdt_walk_kernel<true><<<grid, block, 0, stream>>>(
            x, root_nodes, root_biases, tree_indices,
            nodes_lv, biases_lv, leaf_nodes, packed, out);
    } else {
        gbdt_walk_kernel<false><<<grid, block, 0, stream>>>(
            x, root_nodes, root_biases, tree_indices,
            nodes_lv, biases_lv, leaf_nodes, (const int2*)nullptr, out);
    }
}